// Round 7
// baseline (319.363 us; speedup 1.0000x reference)
//
#include <hip/hip_runtime.h>
#include <float.h>
#include <math.h>

// Problem constants (from reference setup_inputs)
#define B_   32
#define D_   128
#define T_   2048
#define K_   2048
#define N_   (B_ * T_)      // 65536

typedef _Float16 f16;
typedef f16   f16x8 __attribute__((ext_vector_type(8)));
typedef f16   f16x4 __attribute__((ext_vector_type(4)));
typedef f16   f16x2 __attribute__((ext_vector_type(2)));
typedef float f32x4 __attribute__((ext_vector_type(4)));

// async global->LDS, 16 B per lane, LDS dst = wave-uniform base + lane*16
__device__ __forceinline__ void load_lds16(const void* g, void* l) {
    __builtin_amdgcn_global_load_lds(
        (const __attribute__((address_space(1))) unsigned int*)g,
        (__attribute__((address_space(3))) unsigned int*)l, 16, 0, 0);
}

// ---------------------------------------------------------------------------
// emb -> (eh, el) fp16 split + halfnorm. One wave per code.
// Also zeroes cnt[k], sum_new[k][:], and the 3 scalar accumulators.
// ---------------------------------------------------------------------------
__global__ void eprep_kernel(const float* __restrict__ emb, f16* __restrict__ eh,
                             f16* __restrict__ el, float* __restrict__ hn,
                             int* __restrict__ cnt, float* __restrict__ scalars,
                             float* __restrict__ sum_new) {
    int k = blockIdx.x;
    int l = threadIdx.x;            // 64
    if (l == 0) cnt[k] = 0;
    if (k == 0 && l < 3) scalars[l] = 0.0f;
    sum_new[(size_t)k * D_ + l]      = 0.0f;
    sum_new[(size_t)k * D_ + 64 + l] = 0.0f;
    float a = emb[(size_t)k * D_ + l];
    float b = emb[(size_t)k * D_ + 64 + l];
    f16 ah = (f16)a; f16 al = (f16)(a - (float)ah);
    f16 bh = (f16)b; f16 bl = (f16)(b - (float)bh);
    eh[(size_t)k * D_ + l]      = ah;
    eh[(size_t)k * D_ + 64 + l] = bh;
    el[(size_t)k * D_ + l]      = al;
    el[(size_t)k * D_ + 64 + l] = bl;
    float s = a * a + b * b;
#pragma unroll
    for (int off = 32; off > 0; off >>= 1) s += __shfl_down(s, off, 64);
    if (l == 0) hn[k] = 0.5f * s;
}

// ---------------------------------------------------------------------------
// Fused transpose-split + MFMA distance-argmin.
// dot(z,e) = zh.eh + zl.eh + zh.el  (split-fp16, error ~2^-22 |z.e|)
// Block = 512 threads (8 waves), 128 rows x ALL 2048 codes (8 groups of 256).
// LDS: AZH 32K + AZL 32K + BS 64K = 128 KB -> 1 block/CU.
// Wave tile 64 rows x 64 codes (2x4 wave grid) -> LDS fragment traffic
// ~77 B/cyc (below the ~85-128 B/cyc LDS ceiling that throttled round 6's
// 32x64 tiles at ~105 B/cyc).
// Phase 0 transposes z[b,:,t-range] via a 32 KB fp32 scratch in BS into
// AZH/AZL (swizzled) and writes global zh/zl for segsum (prep fused away).
// Epilogue: per-row argmin -> idx[n] + fused inverted-index count atomic.
// ---------------------------------------------------------------------------
__global__ __launch_bounds__(512, 2)
void argmin_fused(const float* __restrict__ z, const f16* __restrict__ eh,
                  const f16* __restrict__ el, const float* __restrict__ hn,
                  f16* __restrict__ zh, f16* __restrict__ zl,
                  int* __restrict__ idx, int* __restrict__ cnt,
                  int* __restrict__ pos) {
    __shared__ __align__(16) f16 AZH[128 * 128];   // 32 KB
    __shared__ __align__(16) f16 AZL[128 * 128];   // 32 KB
    __shared__ __align__(16) f16 BS[256 * 128];    // 64 KB (also 32 KB fp32 scratch)
    float* SCR = (float*)BS;                       // 64 t x 128 d fp32, swizzled

    const int tid = threadIdx.x;
    const int w   = tid >> 6;            // wave 0..7
    const int l   = tid & 63;
    const int c15 = l & 15;
    const int q   = l >> 4;
    const int wm  = w >> 2;              // row half (64 rows)
    const int wn  = w & 3;               // code quarter (64 codes of 256-group)
    const int n0  = blockIdx.x * 128;    // 512 blocks; rows stay within one b
    const int b   = n0 >> 11;            // T = 2048
    const int t0  = n0 & (T_ - 1);
    const float* zb = z + (size_t)b * D_ * T_ + t0;

    // ---- phase 0: transpose z -> AZH/AZL (+ global zh/zl), 2 chunks of 64 t
    for (int c = 0; c < 2; c++) {
        __syncthreads();                 // SCR free (prev chunk readers done)
#pragma unroll
        for (int it = 0; it < 4; it++) {
            int flat = it * 512 + tid;   // 128 d x 16 tq
            int d  = flat >> 4;
            int tq = flat & 15;
            float4 v = *(const float4*)(zb + (size_t)d * T_ + c * 64 + tq * 4);
            int t;
            t = tq * 4 + 0; SCR[t * 128 + (d ^ (t & 31))] = v.x;
            t = tq * 4 + 1; SCR[t * 128 + (d ^ (t & 31))] = v.y;
            t = tq * 4 + 2; SCR[t * 128 + (d ^ (t & 31))] = v.z;
            t = tq * 4 + 3; SCR[t * 128 + (d ^ (t & 31))] = v.w;
        }
        __syncthreads();
        const int rl = tid >> 3;         // 0..63 (t within chunk)
        const int d0 = (tid & 7) * 16;
        const int m  = c * 64 + rl;      // row within A tile
#pragma unroll
        for (int g = 0; g < 2; g++) {
            f16x8 hv, lv;
#pragma unroll
            for (int j = 0; j < 8; j++) {
                int d = d0 + g * 8 + j;
                float v = SCR[rl * 128 + (d ^ (rl & 31))];
                f16 hh = (f16)v;
                hv[j] = hh;
                lv[j] = (f16)(v - (float)hh);
            }
            int gg = (d0 >> 3) + g;
            int sg = gg ^ (m & 15);      // reader convention: glob G at LDS G^(m&15)
            *(f16x8*)&AZH[m * 128 + sg * 8] = hv;
            *(f16x8*)&AZL[m * 128 + sg * 8] = lv;
            *(f16x8*)&zh[(size_t)(n0 + m) * D_ + d0 + g * 8] = hv;
            *(f16x8*)&zl[(size_t)(n0 + m) * D_ + d0 + g * 8] = lv;
        }
    }

    float minv[4][4];
    int   mini[4][4];
#pragma unroll
    for (int mi = 0; mi < 4; mi++)
#pragma unroll
        for (int r = 0; r < 4; r++) { minv[mi][r] = FLT_MAX; mini[mi][r] = 0x7fffffff; }

    // ---- main loop: 8 groups of 256 codes
    for (int g8 = 0; g8 < 8; g8++) {
        const int k0 = g8 * 256;
        f32x4 acc[4][4];
#pragma unroll
        for (int mi = 0; mi < 4; mi++)
#pragma unroll
            for (int ni = 0; ni < 4; ni++) acc[mi][ni] = (f32x4){0.f, 0.f, 0.f, 0.f};

        // phase eh: zh.eh + zl.eh
        __syncthreads();                 // BS free (also orders phase-0 A writes)
#pragma unroll
        for (int i = 0; i < 8; i++) {
            int cl = w * 32 + i * 4 + q;
            int gg = c15 ^ (cl & 15);
            load_lds16(eh + (size_t)(k0 + cl) * D_ + gg * 8, &BS[(w * 32 + i * 4) * 128]);
        }
        __syncthreads();                 // drain
#pragma unroll
        for (int s = 0; s < 4; s++) {
            const int gp = (s * 4 + q) ^ c15;
            f16x8 a_h[4], a_l[4], bf[4];
#pragma unroll
            for (int mi = 0; mi < 4; mi++) {
                int m = wm * 64 + mi * 16 + c15;
                a_h[mi] = *(const f16x8*)&AZH[m * 128 + gp * 8];
                a_l[mi] = *(const f16x8*)&AZL[m * 128 + gp * 8];
            }
#pragma unroll
            for (int ni = 0; ni < 4; ni++) {
                int n = wn * 64 + ni * 16 + c15;
                bf[ni] = *(const f16x8*)&BS[n * 128 + gp * 8];
            }
#pragma unroll
            for (int mi = 0; mi < 4; mi++)
#pragma unroll
                for (int ni = 0; ni < 4; ni++) {
                    acc[mi][ni] = __builtin_amdgcn_mfma_f32_16x16x32_f16(
                        a_h[mi], bf[ni], acc[mi][ni], 0, 0, 0);
                    acc[mi][ni] = __builtin_amdgcn_mfma_f32_16x16x32_f16(
                        a_l[mi], bf[ni], acc[mi][ni], 0, 0, 0);
                }
        }

        // phase el: zh.el
        __syncthreads();
#pragma unroll
        for (int i = 0; i < 8; i++) {
            int cl = w * 32 + i * 4 + q;
            int gg = c15 ^ (cl & 15);
            load_lds16(el + (size_t)(k0 + cl) * D_ + gg * 8, &BS[(w * 32 + i * 4) * 128]);
        }
        __syncthreads();
#pragma unroll
        for (int s = 0; s < 4; s++) {
            const int gp = (s * 4 + q) ^ c15;
            f16x8 a_h[4], bf[4];
#pragma unroll
            for (int mi = 0; mi < 4; mi++) {
                int m = wm * 64 + mi * 16 + c15;
                a_h[mi] = *(const f16x8*)&AZH[m * 128 + gp * 8];
            }
#pragma unroll
            for (int ni = 0; ni < 4; ni++) {
                int n = wn * 64 + ni * 16 + c15;
                bf[ni] = *(const f16x8*)&BS[n * 128 + gp * 8];
            }
#pragma unroll
            for (int mi = 0; mi < 4; mi++)
#pragma unroll
                for (int ni = 0; ni < 4; ni++)
                    acc[mi][ni] = __builtin_amdgcn_mfma_f32_16x16x32_f16(
                        a_h[mi], bf[ni], acc[mi][ni], 0, 0, 0);
        }

        // running argmin (codes ascend across g8, ni; strict < = first-min)
#pragma unroll
        for (int ni = 0; ni < 4; ni++) {
            int   k = k0 + wn * 64 + ni * 16 + c15;
            float h = hn[k];
#pragma unroll
            for (int mi = 0; mi < 4; mi++)
#pragma unroll
                for (int r = 0; r < 4; r++) {
                    float sc = h - acc[mi][ni][r];
                    if (sc < minv[mi][r]) { minv[mi][r] = sc; mini[mi][r] = k; }
                }
        }
    }

    // ---- epilogue: 16-lane shfl reduce, cross-wn LDS reduce, idx + count
    __syncthreads();                     // all BS reads done; alias as reduce buf
    float* redv = (float*)BS;            // [128][4]
    int*   redi = (int*)(redv + 512);
#pragma unroll
    for (int mi = 0; mi < 4; mi++)
#pragma unroll
        for (int r = 0; r < 4; r++) {
            float bv = minv[mi][r];
            int   bi = mini[mi][r];
#pragma unroll
            for (int msk = 1; msk < 16; msk <<= 1) {
                float ov = __shfl_xor(bv, msk, 64);
                int   oi = __shfl_xor(bi, msk, 64);
                if (ov < bv || (ov == bv && oi < bi)) { bv = ov; bi = oi; }
            }
            if (c15 == 0) {
                int row = wm * 64 + mi * 16 + q * 4 + r;
                redv[row * 4 + wn] = bv;
                redi[row * 4 + wn] = bi;
            }
        }
    __syncthreads();
    if (tid < 128) {
        float bv = redv[tid * 4];
        int   bi = redi[tid * 4];
#pragma unroll
        for (int j = 1; j < 4; j++) {
            float v = redv[tid * 4 + j];
            int   i = redi[tid * 4 + j];
            if (v < bv || (v == bv && i < bi)) { bv = v; bi = i; }
        }
        int n = n0 + tid;
        idx[n] = bi;
        pos[n] = atomicAdd(&cnt[bi], 1);     // fused assign
    }
}

// ---------------------------------------------------------------------------
// Exclusive prefix sum over 2048 counts, single block of 256 threads.
// ---------------------------------------------------------------------------
__global__ __launch_bounds__(256)
void scan_kernel(const int* __restrict__ cnt, int* __restrict__ offs) {
    __shared__ int part[256];
    const int tid = threadIdx.x;
    int loc[8];
    int s = 0;
#pragma unroll
    for (int j = 0; j < 8; j++) { loc[j] = s; s += cnt[tid * 8 + j]; }
    part[tid] = s;
    __syncthreads();
    for (int off = 1; off < 256; off <<= 1) {
        int v = (tid >= off) ? part[tid - off] : 0;
        __syncthreads();
        part[tid] += v;
        __syncthreads();
    }
    int pre = (tid == 0) ? 0 : part[tid - 1];
#pragma unroll
    for (int j = 0; j < 8; j++) offs[tid * 8 + j] = pre + loc[j];
    if (tid == 255) offs[2048] = pre + s;    // == N
}

// ---------------------------------------------------------------------------
// STE output + loss + fused bucket scatter (row_list build).
// Block = 64 t x 128 d tile of one b. Coalesced float4 read/write.
// ---------------------------------------------------------------------------
__global__ __launch_bounds__(256)
void ste_kernel(const float* __restrict__ z, const float* __restrict__ emb,
                const int* __restrict__ idx, const int* __restrict__ pos,
                const int* __restrict__ offs, float* __restrict__ out0,
                int* __restrict__ row_list, float* __restrict__ s_loss) {
    __shared__ int   scode[64];
    __shared__ float red[256];
    const int tid = threadIdx.x;
    const int blk = blockIdx.x;              // 1024
    const int b   = blk >> 5;
    const int t0  = (blk & 31) * 64;
    const int n0  = b * T_ + t0;
    if (tid < 64) {
        int n = n0 + tid;
        int code = idx[n];
        scode[tid] = code;
        row_list[offs[code] + pos[n]] = n;   // fused bucket
    }
    __syncthreads();

    const float* zb = z    + (size_t)b * D_ * T_ + t0;
    float*       ob = out0 + (size_t)b * D_ * T_ + t0;
    float lsum = 0.0f;
#pragma unroll
    for (int it = 0; it < 8; it++) {
        int flat = it * 256 + tid;
        int d = flat >> 4;
        int q = flat & 15;
        float4 zv = *(const float4*)(zb + (size_t)d * T_ + q * 4);
        float zi[4] = {zv.x, zv.y, zv.z, zv.w};
        float ov[4];
#pragma unroll
        for (int j = 0; j < 4; j++) {
            int code = scode[q * 4 + j];
            float e  = emb[(size_t)code * D_ + d];
            float df = e - zi[j];            // z_vq - zf (one rounding)
            ov[j] = zi[j] + df;              // zf + (z_vq - zf), matches reference STE
            lsum += df * df;
        }
        float4 o4 = {ov[0], ov[1], ov[2], ov[3]};
        *(float4*)(ob + (size_t)d * T_ + q * 4) = o4;
    }

    red[tid] = lsum;
    __syncthreads();
    for (int s = 128; s > 0; s >>= 1) {
        if (tid < s) red[tid] += red[tid + s];
        __syncthreads();
    }
    if (tid == 0) atomicAdd(s_loss, red[0]);
}

// ---------------------------------------------------------------------------
// Segment sum, balanced by ROW: wave per 64 consecutive row_list entries
// (code-sorted). Lane l owns d-pair {2l,2l+1}; wave walks rows via shfl
// broadcast; flushes partials with 2 fp32 atomics/lane at code boundaries.
// ---------------------------------------------------------------------------
__global__ __launch_bounds__(64)
void segsum_kernel(const f16* __restrict__ zh, const f16* __restrict__ zl,
                   const int* __restrict__ row_list, const int* __restrict__ idx,
                   float* __restrict__ sum_new) {
    const int l = threadIdx.x;           // 64
    const int base = blockIdx.x * 64;    // 1024 blocks
    int myrow  = row_list[base + l];
    int mycode = idx[myrow];
    float ax = 0.0f, ay = 0.0f;
    int cur = __shfl(mycode, 0, 64);
#pragma unroll 8
    for (int i = 0; i < 64; i++) {
        int r = __shfl(myrow, i, 64);
        int c = __shfl(mycode, i, 64);
        if (c != cur) {                  // wave-uniform branch
            atomicAdd(&sum_new[(size_t)cur * D_ + l * 2],     ax);
            atomicAdd(&sum_new[(size_t)cur * D_ + l * 2 + 1], ay);
            ax = 0.0f; ay = 0.0f; cur = c;
        }
        f16x2 hv = *(const f16x2*)&zh[(size_t)r * D_ + l * 2];
        f16x2 lv = *(const f16x2*)&zl[(size_t)r * D_ + l * 2];
        ax += (float)hv.x + (float)lv.x;
        ay += (float)hv.y + (float)lv.y;
    }
    atomicAdd(&sum_new[(size_t)cur * D_ + l * 2],     ax);
    atomicAdd(&sum_new[(size_t)cur * D_ + l * 2 + 1], ay);
}

// ---------------------------------------------------------------------------
// EMA update, emb_new select, dk / entropy partial sums.
// elem_new derived from offs (counts).
// ---------------------------------------------------------------------------
__global__ __launch_bounds__(256)
void update_kernel(const float* __restrict__ emb, const float* __restrict__ emb_sum,
                   const float* __restrict__ emb_elem, const float* __restrict__ emb_rand,
                   const float* __restrict__ sum_new, const int* __restrict__ offs,
                   float* __restrict__ out_emb_new, float* __restrict__ out_emb_sum_n,
                   float* __restrict__ out_emb_elem_n,
                   float* __restrict__ s_ent, float* __restrict__ s_dk) {
    const float MU  = 0.99f;
    const float OMM = (float)(1.0 - 0.99);   // match JAX's fp64 1.0-0.99 -> fp32
    int gid = blockIdx.x * 256 + threadIdx.x;   // < K_*D_ = 262144
    int k = gid >> 7;
    int d = gid & 127;

    float sn = sum_new[gid];
    float es = emb_sum[gid];
    float en = (float)(offs[k + 1] - offs[k]);
    float ee = emb_elem[k];
    float esn = MU * es + OMM * sn;
    float een = MU * ee + OMM * en;
    out_emb_sum_n[gid] = esn;
    float enew = (een >= 1.0f) ? (esn / een) : emb_rand[gid];
    out_emb_new[gid] = enew;

    float df = enew - emb[gid];
    float v  = df * df;
    __shared__ float red[256];
    red[threadIdx.x] = v;
    __syncthreads();
    for (int s = 128; s > 0; s >>= 1) {
        if (threadIdx.x < s) red[threadIdx.x] += red[threadIdx.x + s];
        __syncthreads();
    }
    if (threadIdx.x == 0) atomicAdd(s_dk, red[0]);

    if (d == 0) {
        out_emb_elem_n[k] = een;
        float p = en * (1.0f / 65536.0f);   // sum(elem_new) == N exactly in fp32
        atomicAdd(s_ent, p * logf(p + 1e-8f));
    }
}

// ---------------------------------------------------------------------------
// Scalar finalization
// ---------------------------------------------------------------------------
__global__ void final_kernel(const float* __restrict__ s_loss, const float* __restrict__ s_ent,
                             const float* __restrict__ s_dk,
                             float* __restrict__ out_loss, float* __restrict__ out_ent,
                             float* __restrict__ out_dk) {
    out_loss[0] = s_loss[0];
    out_ent[0]  = expf(-s_ent[0]);
    out_dk[0]   = sqrtf(s_dk[0]) * (1.0f / 512.0f);   // sqrt(K*D) = 512
}

// ---------------------------------------------------------------------------
extern "C" void kernel_launch(void* const* d_in, const int* in_sizes, int n_in,
                              void* d_out, int out_size, void* d_ws, size_t ws_size,
                              hipStream_t stream) {
    (void)in_sizes; (void)n_in; (void)out_size; (void)ws_size;

    const float* z        = (const float*)d_in[0];   // [32,128,2048]
    const float* emb      = (const float*)d_in[1];   // [2048,128]
    const float* emb_sum  = (const float*)d_in[2];   // [2048,128]
    const float* emb_elem = (const float*)d_in[3];   // [2048]
    const float* emb_rand = (const float*)d_in[4];   // [2048,128]

    float* out = (float*)d_out;
    float* out0            = out;                            // z_vq_out  8388608
    float* out_loss        = out + 8388608;                  // scalar
    float* out_emb_new     = out + 8388609;                  // 262144
    float* out_emb_sum_n   = out + 8388609 + 262144;         // 262144
    float* out_emb_elem_n  = out + 8388609 + 524288;         // 2048
    float* out_ent         = out + 8388609 + 524288 + 2048;  // scalar
    float* out_dk          = out_ent + 1;                    // scalar

    float* ws = (float*)d_ws;                     // offsets in floats
    f16*   zh       = (f16*)(ws);                 // 8388608 halves (4194304 f)
    f16*   zl       = (f16*)(ws + 4194304);       // 8388608 halves
    int*   idx      = (int*)(ws + 8388608);       // 65536
    float* hn       = ws + 8454144;               // 2048
    f16*   eh       = (f16*)(ws + 8456192);       // 262144 halves (131072 f)
    f16*   el       = (f16*)(ws + 8587264);       // 262144 halves
    float* sum_new  = ws + 8718336;               // 262144
    int*   cnt      = (int*)(ws + 8980480);       // 2048
    float* scalars  = ws + 8982528;               // s_loss, s_ent, s_dk
    float* s_loss   = scalars;
    float* s_ent    = scalars + 1;
    float* s_dk     = scalars + 2;
    int*   pos      = (int*)(ws + 8982531);       // 65536
    int*   offs     = (int*)(ws + 9048067);       // 2049
    int*   row_list = (int*)(ws + 9050116);       // 65536
                                                  // end 9115652 f ~ 36.5 MB

    eprep_kernel<<<K_, 64, 0, stream>>>(emb, eh, el, hn, cnt, scalars, sum_new);
    argmin_fused<<<N_ / 128, 512, 0, stream>>>(z, eh, el, hn, zh, zl, idx, cnt, pos);
    scan_kernel<<<1, 256, 0, stream>>>(cnt, offs);
    ste_kernel<<<B_ * (T_ / 64), 256, 0, stream>>>(z, emb, idx, pos, offs, out0,
                                                   row_list, s_loss);
    segsum_kernel<<<N_ / 64, 64, 0, stream>>>(zh, zl, row_list, idx, sum_new);
    update_kernel<<<(K_ * D_) / 256, 256, 0, stream>>>(emb, emb_sum, emb_elem, emb_rand,
                                                       sum_new, offs,
                                                       out_emb_new, out_emb_sum_n,
                                                       out_emb_elem_n, s_ent, s_dk);
    final_kernel<<<1, 1, 0, stream>>>(s_loss, s_ent, s_dk, out_loss, out_ent, out_dk);
}